// Round 1
// baseline (518.518 us; speedup 1.0000x reference)
//
#include <hip/hip_runtime.h>

typedef __attribute__((ext_vector_type(8))) short short8;
typedef __attribute__((ext_vector_type(4))) float floatx4;
typedef __attribute__((ext_vector_type(4))) int intx4;

#define NPIX 4096
#define CH 256

static __device__ __forceinline__ unsigned short f2bf(float f) {
  union { float f; unsigned int u; } v; v.f = f;
  unsigned int u = v.u;
  return (unsigned short)((u + 0x7FFFu + ((u >> 16) & 1u)) >> 16);
}

// ---------------- weights fp32 -> bf16 ----------------
__global__ void conv_weights_kernel(const float* __restrict__ wq, const float* __restrict__ wk,
                                    const float* __restrict__ wv, const float* __restrict__ wo,
                                    unsigned short* __restrict__ wqkv, unsigned short* __restrict__ wob) {
  int i = blockIdx.x * 256 + threadIdx.x;   // 0..65535
  wqkv[i]          = f2bf(wq[i]);
  wqkv[65536 + i]  = f2bf(wk[i]);
  wqkv[131072 + i] = f2bf(wv[i]);
  wob[i]           = f2bf(wo[i]);
}

// ---------------- GroupNorm -> xnT bf16 [b][n][c] ----------------
__global__ __launch_bounds__(256) void gn_kernel(const float* __restrict__ x,
                                                 const float* __restrict__ gsc,
                                                 const float* __restrict__ gbi,
                                                 unsigned short* __restrict__ xnT) {
  int blk = blockIdx.x; int b = blk >> 5; int g = blk & 31;
  int c0 = g * 8;
  const float* xb = x + ((size_t)b * CH + c0) * NPIX;
  int tid = threadIdx.x;
  float s = 0.f, ss = 0.f;
  for (int ci = 0; ci < 8; ++ci) {
    const float* p = xb + ci * NPIX;
    for (int n = tid; n < NPIX; n += 256) { float v = p[n]; s += v; ss += v * v; }
  }
#pragma unroll
  for (int o = 32; o > 0; o >>= 1) { s += __shfl_down(s, o); ss += __shfl_down(ss, o); }
  __shared__ float red[10];
  int wid = tid >> 6;
  if ((tid & 63) == 0) { red[wid] = s; red[4 + wid] = ss; }
  __syncthreads();
  if (tid == 0) {
    float S = red[0] + red[1] + red[2] + red[3];
    float SS = red[4] + red[5] + red[6] + red[7];
    float mean = S * (1.f / 32768.f);
    float var = SS * (1.f / 32768.f) - mean * mean;
    red[8] = mean; red[9] = rsqrtf(var + 1e-5f);
  }
  __syncthreads();
  float mean = red[8], rstd = red[9];
  float sc[8], bi[8];
#pragma unroll
  for (int ci = 0; ci < 8; ++ci) {
    float scale = gsc[c0 + ci] * rstd;
    sc[ci] = scale;
    bi[ci] = gbi[c0 + ci] - mean * scale;
  }
  for (int n = tid; n < NPIX; n += 256) {
    alignas(16) unsigned short tmp[8];
#pragma unroll
    for (int ci = 0; ci < 8; ++ci) {
      float v = xb[(size_t)ci * NPIX + n];
      tmp[ci] = f2bf(v * sc[ci] + bi[ci]);
    }
    *(intx4*)(xnT + ((size_t)(b * NPIX + n)) * CH + c0) = *(const intx4*)tmp;
  }
}

// ---------------- QKV GEMM: D[o,n] = sum_c W[o,c]*xnT[n,c] + bias ----------------
// q,k written [n][o] bf16 ; v written [o][n] bf16
__global__ __launch_bounds__(256, 2) void qkv_gemm(
    const unsigned short* __restrict__ wqkv, const unsigned short* __restrict__ xnT,
    const float* __restrict__ bq, const float* __restrict__ bk, const float* __restrict__ bv,
    unsigned short* __restrict__ qT, unsigned short* __restrict__ kT, unsigned short* __restrict__ vC) {
  int nt = blockIdx.x, ot = blockIdx.y, bz = blockIdx.z;
  int which = bz % 3, b = bz / 3;
  const unsigned short* W = wqkv + which * 65536;
  const float* bias = which == 0 ? bq : (which == 1 ? bk : bv);
  const unsigned short* X = xnT + (size_t)b * NPIX * CH;
  int o0 = ot * 128, n0 = nt * 128;

  __shared__ unsigned short As[128 * 64];
  __shared__ unsigned short Bs[128 * 64];

  int tid = threadIdx.x;
  int wave = tid >> 6, lane = tid & 63, quad = lane >> 4, l16 = lane & 15;
  int wm = (wave >> 1) * 64, wn = (wave & 1) * 64;

  floatx4 acc[4][4];
#pragma unroll
  for (int i = 0; i < 4; ++i)
#pragma unroll
    for (int j = 0; j < 4; ++j) acc[i][j] = (floatx4){0.f, 0.f, 0.f, 0.f};

  for (int k0 = 0; k0 < 256; k0 += 64) {
    __syncthreads();
#pragma unroll
    for (int i = 0; i < 4; ++i) {
      int idx = tid + i * 256;            // 0..1023
      int row = idx >> 3, ch = idx & 7;
      int phys = ch ^ (row & 7);
      *(intx4*)(As + row * 64 + phys * 8) = *(const intx4*)(W + (size_t)(o0 + row) * CH + k0 + ch * 8);
      *(intx4*)(Bs + row * 64 + phys * 8) = *(const intx4*)(X + (size_t)(n0 + row) * CH + k0 + ch * 8);
    }
    __syncthreads();
#pragma unroll
    for (int s = 0; s < 2; ++s) {
      short8 af[4], bf[4];
#pragma unroll
      for (int i = 0; i < 4; ++i) {
        int m = wm + i * 16 + l16;
        af[i] = *(const short8*)(As + m * 64 + (((s * 4 + quad) ^ (m & 7)) * 8));
        int n = wn + i * 16 + l16;
        bf[i] = *(const short8*)(Bs + n * 64 + (((s * 4 + quad) ^ (n & 7)) * 8));
      }
#pragma unroll
      for (int i = 0; i < 4; ++i)
#pragma unroll
        for (int j = 0; j < 4; ++j)
          acc[i][j] = __builtin_amdgcn_mfma_f32_16x16x32_bf16(af[i], bf[j], acc[i][j], 0, 0, 0);
    }
  }

  if (which < 2) {
    unsigned short* outp = (which == 0 ? qT : kT) + (size_t)b * NPIX * CH;
#pragma unroll
    for (int i = 0; i < 4; ++i) {
      int obase = o0 + wm + i * 16 + quad * 4;
      float bias4[4];
#pragma unroll
      for (int r = 0; r < 4; ++r) bias4[r] = bias[obase + r];
#pragma unroll
      for (int j = 0; j < 4; ++j) {
        int n = n0 + wn + j * 16 + l16;
        unsigned long long pk = 0;
#pragma unroll
        for (int r = 0; r < 4; ++r)
          pk |= (unsigned long long)f2bf(acc[i][j][r] + bias4[r]) << (16 * r);
        *(unsigned long long*)(outp + (size_t)n * CH + obase) = pk;
      }
    }
  } else {
    unsigned short* outp = vC + (size_t)b * CH * NPIX;
#pragma unroll
    for (int i = 0; i < 4; ++i)
#pragma unroll
      for (int r = 0; r < 4; ++r) {
        int o = o0 + wm + i * 16 + quad * 4 + r;
        float bb = bias[o];
#pragma unroll
        for (int j = 0; j < 4; ++j) {
          int n = n0 + wn + j * 16 + l16;
          outp[(size_t)o * NPIX + n] = f2bf(acc[i][j][r] + bb);
        }
      }
  }
}

// ---------------- flash attention ----------------
// grid (64, 8), block 256 (4 waves x 16 Q-rows). KTILE=32.
__global__ __launch_bounds__(256, 2) void attn_kernel(
    const unsigned short* __restrict__ qT, const unsigned short* __restrict__ kT,
    const unsigned short* __restrict__ vC, unsigned short* __restrict__ aT) {
  __shared__ unsigned short Klds[32 * 256];   // [m][c], chunk-swizzled
  __shared__ unsigned short Vlds[256 * 32];   // [c][m], chunk-swizzled
  __shared__ unsigned short Plds[4][16 * 32]; // per-wave P buffer

  const int tid = threadIdx.x;
  const int wave = tid >> 6, lane = tid & 63;
  const int quad = lane >> 4, l16 = lane & 15;
  const int b = blockIdx.y;
  const int n_base = blockIdx.x * 64 + wave * 16;

  const unsigned short* Kb = kT + (size_t)b * NPIX * CH;
  const unsigned short* Vb = vC + (size_t)b * CH * NPIX;

  short8 qf[8];
  {
    const unsigned short* qp = qT + ((size_t)(b * NPIX + n_base + l16)) * CH + quad * 8;
#pragma unroll
    for (int s = 0; s < 8; ++s) qf[s] = *(const short8*)(qp + s * 32);
  }

  floatx4 oacc[16];
#pragma unroll
  for (int j = 0; j < 16; ++j) oacc[j] = (floatx4){0.f, 0.f, 0.f, 0.f};
  float m_i[4], l_i[4];
#pragma unroll
  for (int r = 0; r < 4; ++r) { m_i[r] = -1e30f; l_i[r] = 0.f; }

  unsigned short* Pw = Plds[wave];

  for (int kt = 0; kt < 128; ++kt) {
    const int m0 = kt * 32;
    __syncthreads();
#pragma unroll
    for (int i = 0; i < 4; ++i) {
      int idx = tid + i * 256;  // 0..1023
      int rk = idx >> 5, ck = idx & 31;
      *(intx4*)(Klds + rk * 256 + ((ck ^ (rk & 7)) * 8)) =
          *(const intx4*)(Kb + (size_t)(m0 + rk) * CH + ck * 8);
      int rv = idx >> 2, cv = idx & 3;
      *(intx4*)(Vlds + rv * 32 + ((cv ^ ((rv >> 1) & 3)) * 8)) =
          *(const intx4*)(Vb + (size_t)rv * NPIX + m0 + cv * 8);
    }
    __syncthreads();

    floatx4 sacc[2];
    sacc[0] = (floatx4){0.f, 0.f, 0.f, 0.f};
    sacc[1] = (floatx4){0.f, 0.f, 0.f, 0.f};
#pragma unroll
    for (int s = 0; s < 8; ++s) {
#pragma unroll
      for (int j = 0; j < 2; ++j) {
        int ml = j * 16 + l16;
        short8 kf = *(const short8*)(Klds + ml * 256 + (((s * 4 + quad) ^ (ml & 7)) * 8));
        sacc[j] = __builtin_amdgcn_mfma_f32_16x16x32_bf16(qf[s], kf, sacc[j], 0, 0, 0);
      }
    }
    sacc[0] *= 0.0625f; sacc[1] *= 0.0625f;

    float alpha[4];
#pragma unroll
    for (int r = 0; r < 4; ++r) {
      float mx = fmaxf(sacc[0][r], sacc[1][r]);
#pragma unroll
      for (int msk = 1; msk < 16; msk <<= 1) mx = fmaxf(mx, __shfl_xor(mx, msk));
      float mn = fmaxf(m_i[r], mx);
      alpha[r] = __expf(m_i[r] - mn);
      m_i[r] = mn;
      float p0 = __expf(sacc[0][r] - mn);
      float p1 = __expf(sacc[1][r] - mn);
      sacc[0][r] = p0; sacc[1][r] = p1;
      float sum = p0 + p1;
#pragma unroll
      for (int msk = 1; msk < 16; msk <<= 1) sum += __shfl_xor(sum, msk);
      l_i[r] = l_i[r] * alpha[r] + sum;
    }
    // P (C-layout) -> per-wave LDS buffer
#pragma unroll
    for (int j = 0; j < 2; ++j)
#pragma unroll
      for (int r = 0; r < 4; ++r) {
        int row = quad * 4 + r, col = j * 16 + l16;
        int phys = (col >> 3) ^ ((row >> 1) & 3);
        Pw[row * 32 + phys * 8 + (col & 7)] = f2bf(sacc[j][r]);
      }
    // rescale O while the P writes drain
#pragma unroll
    for (int j = 0; j < 16; ++j)
#pragma unroll
      for (int r = 0; r < 4; ++r) oacc[j][r] *= alpha[r];
    asm volatile("s_waitcnt lgkmcnt(0)" ::: "memory");
    short8 pf = *(const short8*)(Pw + l16 * 32 + ((quad ^ ((l16 >> 1) & 3)) * 8));
#pragma unroll
    for (int j = 0; j < 16; ++j) {
      int c = j * 16 + l16;
      short8 vf = *(const short8*)(Vlds + c * 32 + ((quad ^ ((c >> 1) & 3)) * 8));
      oacc[j] = __builtin_amdgcn_mfma_f32_16x16x32_bf16(pf, vf, oacc[j], 0, 0, 0);
    }
  }

  unsigned short* ab = aT + (size_t)b * NPIX * CH;
  float inv[4];
#pragma unroll
  for (int r = 0; r < 4; ++r) inv[r] = 1.f / l_i[r];
#pragma unroll
  for (int j = 0; j < 16; ++j) {
    int c = j * 16 + l16;
#pragma unroll
    for (int r = 0; r < 4; ++r) {
      int n = n_base + quad * 4 + r;
      ab[(size_t)n * CH + c] = f2bf(oacc[j][r] * inv[r]);
    }
  }
}

// ---------------- output projection + bias + residual ----------------
__global__ __launch_bounds__(256, 2) void out_gemm(
    const unsigned short* __restrict__ wob, const unsigned short* __restrict__ aT,
    const float* __restrict__ bo, const float* __restrict__ x, float* __restrict__ outp) {
  int nt = blockIdx.x, ot = blockIdx.y, b = blockIdx.z;
  const unsigned short* A = aT + (size_t)b * NPIX * CH;
  int o0 = ot * 128, n0 = nt * 128;

  __shared__ unsigned short As[128 * 64];
  __shared__ unsigned short Bs[128 * 64];

  int tid = threadIdx.x;
  int wave = tid >> 6, lane = tid & 63, quad = lane >> 4, l16 = lane & 15;
  int wm = (wave >> 1) * 64, wn = (wave & 1) * 64;

  floatx4 acc[4][4];
#pragma unroll
  for (int i = 0; i < 4; ++i)
#pragma unroll
    for (int j = 0; j < 4; ++j) acc[i][j] = (floatx4){0.f, 0.f, 0.f, 0.f};

  for (int k0 = 0; k0 < 256; k0 += 64) {
    __syncthreads();
#pragma unroll
    for (int i = 0; i < 4; ++i) {
      int idx = tid + i * 256;
      int row = idx >> 3, ch = idx & 7;
      int phys = ch ^ (row & 7);
      *(intx4*)(As + row * 64 + phys * 8) = *(const intx4*)(wob + (size_t)(o0 + row) * CH + k0 + ch * 8);
      *(intx4*)(Bs + row * 64 + phys * 8) = *(const intx4*)(A + (size_t)(n0 + row) * CH + k0 + ch * 8);
    }
    __syncthreads();
#pragma unroll
    for (int s = 0; s < 2; ++s) {
      short8 af[4], bf[4];
#pragma unroll
      for (int i = 0; i < 4; ++i) {
        int m = wm + i * 16 + l16;
        af[i] = *(const short8*)(As + m * 64 + (((s * 4 + quad) ^ (m & 7)) * 8));
        int n = wn + i * 16 + l16;
        bf[i] = *(const short8*)(Bs + n * 64 + (((s * 4 + quad) ^ (n & 7)) * 8));
      }
#pragma unroll
      for (int i = 0; i < 4; ++i)
#pragma unroll
        for (int j = 0; j < 4; ++j)
          acc[i][j] = __builtin_amdgcn_mfma_f32_16x16x32_bf16(af[i], bf[j], acc[i][j], 0, 0, 0);
    }
  }

#pragma unroll
  for (int i = 0; i < 4; ++i)
#pragma unroll
    for (int r = 0; r < 4; ++r) {
      int o = o0 + wm + i * 16 + quad * 4 + r;
      float bb = bo[o];
#pragma unroll
      for (int j = 0; j < 4; ++j) {
        int n = n0 + wn + j * 16 + l16;
        size_t idx = ((size_t)b * CH + o) * NPIX + n;
        outp[idx] = x[idx] + bb + acc[i][j][r];
      }
    }
}

extern "C" void kernel_launch(void* const* d_in, const int* in_sizes, int n_in,
                              void* d_out, int out_size, void* d_ws, size_t ws_size,
                              hipStream_t stream) {
  const float* x   = (const float*)d_in[0];
  const float* gsc = (const float*)d_in[1];
  const float* gbi = (const float*)d_in[2];
  const float* wq  = (const float*)d_in[3];
  const float* bq  = (const float*)d_in[4];
  const float* wk  = (const float*)d_in[5];
  const float* bk  = (const float*)d_in[6];
  const float* wv  = (const float*)d_in[7];
  const float* bv  = (const float*)d_in[8];
  const float* wo  = (const float*)d_in[9];
  const float* bo  = (const float*)d_in[10];
  float* out = (float*)d_out;

  char* ws = (char*)d_ws;
  unsigned short* xnT  = (unsigned short*)(ws);              // 16 MB, reused as aT
  unsigned short* qT   = (unsigned short*)(ws + 16777216);   // 16 MB
  unsigned short* kT   = (unsigned short*)(ws + 33554432);   // 16 MB
  unsigned short* vC   = (unsigned short*)(ws + 50331648);   // 16 MB
  unsigned short* wqkv = (unsigned short*)(ws + 67108864);   // 384 KB
  unsigned short* wob  = (unsigned short*)(ws + 67502080);   // 128 KB
  unsigned short* aT   = xnT;  // alias: xnT dead after qkv_gemm

  conv_weights_kernel<<<256, 256, 0, stream>>>(wq, wk, wv, wo, wqkv, wob);
  gn_kernel<<<256, 256, 0, stream>>>(x, gsc, gbi, xnT);
  dim3 g1(32, 2, 24);
  qkv_gemm<<<g1, 256, 0, stream>>>(wqkv, xnT, bq, bk, bv, qT, kT, vC);
  dim3 g2(64, 8);
  attn_kernel<<<g2, 256, 0, stream>>>(qT, kT, vC, aT);
  dim3 g3(32, 2, 8);
  out_gemm<<<g3, 256, 0, stream>>>(wob, aT, bo, x, out);
}